// Round 19
// baseline (948.095 us; speedup 1.0000x reference)
//
#include <hip/hip_runtime.h>
#include <math.h>

#define BB 32
#define DD 1024
#define SS 4096
#define VVOUT 32003
#define NCHUNK 32
#define ROWS_PER_CHUNK 128
#define PART_STRIDE 1032

// ---- k1: gather embeddings AND prefill gi0 with bih0 -----------------------
__global__ void pre_layer0(const int* __restrict__ tokens, const float* __restrict__ emb,
                           float* __restrict__ embs, const float* __restrict__ bih0,
                           float* __restrict__ gi0) {
  int i = blockIdx.x * 256 + threadIdx.x;
  if (i < 32 * 1024) embs[i] = emb[(size_t)tokens[i >> 10] * DD + (i & 1023)];
  if (i < 32 * 3072) gi0[i] = bih0[i - (i / 3072) * 3072];
}

// ---- k3: gru_act layer0 AND prefill gi1 with bih1 --------------------------
__global__ void act0_fill(const float* __restrict__ gi, const float* __restrict__ bhh,
                          float* __restrict__ h, const float* __restrict__ bih1,
                          float* __restrict__ gi1) {
  int i = blockIdx.x * 256 + threadIdx.x;
  if (i < 32 * 1024) {
    int m = i >> 10, d = i & 1023;
    const float* g = gi + (size_t)m * 3072;
    float ir = g[d], iz = g[d + 1024], inn = g[d + 2048];
    float r = 1.f / (1.f + expf(-(ir + bhh[d])));
    float z = 1.f / (1.f + expf(-(iz + bhh[1024 + d])));
    float nv = tanhf(inn + r * bhh[2048 + d]);
    h[i] = (1.f - z) * nv;
  }
  if (i < 32 * 3072) gi1[i] = bih1[i - (i / 3072) * 3072];
}

// ---- k5: gru_act layer1 AND prefill opre (preoutb) AND out (outb) ----------
__global__ void act1_fill(const float* __restrict__ gi, const float* __restrict__ bhh,
                          float* __restrict__ ht, const float* __restrict__ preoutb,
                          float* __restrict__ opre, const float* __restrict__ outb,
                          float* __restrict__ out) {
  int i = blockIdx.x * 256 + threadIdx.x;
  if (i < 32 * 1024) {
    int m = i >> 10, d = i & 1023;
    const float* g = gi + (size_t)m * 3072;
    float ir = g[d], iz = g[d + 1024], inn = g[d + 2048];
    float r = 1.f / (1.f + expf(-(ir + bhh[d])));
    float z = 1.f / (1.f + expf(-(iz + bhh[1024 + d])));
    float nv = tanhf(inn + r * bhh[2048 + d]);
    ht[i] = (1.f - z) * nv;
    opre[i] = preoutb[d];
  }
  if (i < 32 * VVOUT) out[i] = outb[i - (i / VVOUT) * VVOUT];
}

// ---- GEMM with LDS-staged X (verbatim R16) ---------------------------------
template <int KCHUNK>
__global__ __launch_bounds__(256) void mm_lds(
    float* __restrict__ Y, const float* __restrict__ X, const float* __restrict__ W,
    int N, int ldw, int xld) {
  __shared__ float xs[32][KCHUNK];
  int k0 = blockIdx.y * KCHUNK;
  for (int idx = threadIdx.x; idx < 32 * (KCHUNK / 4); idx += 256) {
    int m = idx / (KCHUNK / 4);
    int i = idx - m * (KCHUNK / 4);
    *(float4*)&xs[m][4 * i] = *(const float4*)(X + (size_t)m * xld + k0 + 4 * i);
  }
  __syncthreads();

  int lane = threadIdx.x & 63;
  int w = threadIdx.x >> 6;
  int c = lane & 3;
  int r = blockIdx.x * 64 + w * 16 + (lane >> 2);
  bool valid = r < N;
  int rr = valid ? r : N - 1;
  const float* wrow = W + (size_t)rr * ldw + k0 + 4 * c;

  float acc[BB];
#pragma unroll
  for (int m = 0; m < BB; m++) acc[m] = 0.f;
#pragma unroll 4
  for (int kk = 0; kk < KCHUNK; kk += 16) {
    float4 w4 = *(const float4*)(wrow + kk);
#pragma unroll
    for (int m = 0; m < BB; m++) {
      float4 x4 = *(const float4*)&xs[m][kk + 4 * c];
      acc[m] = fmaf(w4.x, x4.x, fmaf(w4.y, x4.y, fmaf(w4.z, x4.z, fmaf(w4.w, x4.w, acc[m]))));
    }
  }
#pragma unroll
  for (int m = 0; m < BB; m++) {
    float v = acc[m];
    v += __shfl_xor(v, 1, 64);
    v += __shfl_xor(v, 2, 64);
    if (c == 0 && valid) atomicAdd(&Y[(size_t)m * N + r], v);
  }
}

// ---- logits GEMM, 2-row blocking: one xs read feeds 8 FMAs -----------------
// 4-lane group g owns rows {rb, rb+16}; acc = 64 VGPR -> no spill, 4 w/SIMD.
template <int KCHUNK>
__global__ __launch_bounds__(256) void logits_mm2(
    float* __restrict__ Y, const float* __restrict__ X, const float* __restrict__ W,
    int N, int ldw, int xld) {
  __shared__ float xs[32][KCHUNK];
  int k0 = blockIdx.y * KCHUNK;
  for (int idx = threadIdx.x; idx < 32 * (KCHUNK / 4); idx += 256) {
    int m = idx / (KCHUNK / 4);
    int i = idx - m * (KCHUNK / 4);
    *(float4*)&xs[m][4 * i] = *(const float4*)(X + (size_t)m * xld + k0 + 4 * i);
  }
  __syncthreads();

  int lane = threadIdx.x & 63;
  int w = threadIdx.x >> 6;
  int c = lane & 3;
  int g = lane >> 2;                       // 0..15
  int rb = blockIdx.x * 128 + w * 32 + g;  // rows rb, rb+16
  int r0 = rb, r1 = rb + 16;
  bool v0 = r0 < N, v1 = r1 < N;
  const float* w0p = W + (size_t)(v0 ? r0 : N - 1) * ldw + k0 + 4 * c;
  const float* w1p = W + (size_t)(v1 ? r1 : N - 1) * ldw + k0 + 4 * c;

  float a0[BB], a1[BB];
#pragma unroll
  for (int m = 0; m < BB; m++) { a0[m] = 0.f; a1[m] = 0.f; }

#pragma unroll 4
  for (int kk = 0; kk < KCHUNK; kk += 16) {
    float4 w40 = *(const float4*)(w0p + kk);
    float4 w41 = *(const float4*)(w1p + kk);
#pragma unroll
    for (int m = 0; m < BB; m++) {
      float4 x4 = *(const float4*)&xs[m][kk + 4 * c];
      a0[m] = fmaf(w40.x, x4.x, fmaf(w40.y, x4.y, fmaf(w40.z, x4.z, fmaf(w40.w, x4.w, a0[m]))));
      a1[m] = fmaf(w41.x, x4.x, fmaf(w41.y, x4.y, fmaf(w41.z, x4.z, fmaf(w41.w, x4.w, a1[m]))));
    }
  }
#pragma unroll
  for (int m = 0; m < BB; m++) {
    float s0 = a0[m], s1 = a1[m];
    s0 += __shfl_xor(s0, 1, 64); s0 += __shfl_xor(s0, 2, 64);
    s1 += __shfl_xor(s1, 1, 64); s1 += __shfl_xor(s1, 2, 64);
    if (c == 0) {
      float* Ym = Y + (size_t)m * N;
      if (v0) atomicAdd(&Ym[r0], s0);
      if (v1) atomicAdd(&Ym[r1], s1);
    }
  }
}

// ---- PROBE: R18's 4-row variant, looped (scratch; exposes counters) --------
template <int KCHUNK, int ITER>
__global__ __launch_bounds__(256) void pmm4(
    float* __restrict__ Y, const float* __restrict__ X, const float* __restrict__ W,
    int N, int ldw, int xld) {
  __shared__ float xs[32][KCHUNK];
  int k0 = blockIdx.y * KCHUNK;
  int lane = threadIdx.x & 63;
  int w = threadIdx.x >> 6;
  int c = lane & 3;
  int g = lane >> 2;
  int rb = blockIdx.x * 256 + w * 64 + g;
  int r0 = rb, r1 = rb + 16, r2 = rb + 32, r3 = rb + 48;
  bool v0 = r0 < N, v1 = r1 < N, v2 = r2 < N, v3 = r3 < N;
  const float* w0p = W + (size_t)(v0 ? r0 : N - 1) * ldw + k0 + 4 * c;
  const float* w1p = W + (size_t)(v1 ? r1 : N - 1) * ldw + k0 + 4 * c;
  const float* w2p = W + (size_t)(v2 ? r2 : N - 1) * ldw + k0 + 4 * c;
  const float* w3p = W + (size_t)(v3 ? r3 : N - 1) * ldw + k0 + 4 * c;
  for (int it = 0; it < ITER; it++) {
    for (int idx = threadIdx.x; idx < 32 * (KCHUNK / 4); idx += 256) {
      int m = idx / (KCHUNK / 4);
      int i = idx - m * (KCHUNK / 4);
      *(float4*)&xs[m][4 * i] = *(const float4*)(X + (size_t)m * xld + k0 + 4 * i);
    }
    __syncthreads();
    float a0[BB], a1[BB], a2[BB], a3[BB];
#pragma unroll
    for (int m = 0; m < BB; m++) { a0[m] = 0.f; a1[m] = 0.f; a2[m] = 0.f; a3[m] = 0.f; }
#pragma unroll 2
    for (int kk = 0; kk < KCHUNK; kk += 16) {
      float4 w40 = *(const float4*)(w0p + kk);
      float4 w41 = *(const float4*)(w1p + kk);
      float4 w42 = *(const float4*)(w2p + kk);
      float4 w43 = *(const float4*)(w3p + kk);
#pragma unroll
      for (int m = 0; m < BB; m++) {
        float4 x4 = *(const float4*)&xs[m][kk + 4 * c];
        a0[m] = fmaf(w40.x, x4.x, fmaf(w40.y, x4.y, fmaf(w40.z, x4.z, fmaf(w40.w, x4.w, a0[m]))));
        a1[m] = fmaf(w41.x, x4.x, fmaf(w41.y, x4.y, fmaf(w41.z, x4.z, fmaf(w41.w, x4.w, a1[m]))));
        a2[m] = fmaf(w42.x, x4.x, fmaf(w42.y, x4.y, fmaf(w42.z, x4.z, fmaf(w42.w, x4.w, a2[m]))));
        a3[m] = fmaf(w43.x, x4.x, fmaf(w43.y, x4.y, fmaf(w43.z, x4.z, fmaf(w43.w, x4.w, a3[m]))));
      }
    }
#pragma unroll
    for (int m = 0; m < BB; m++) {
      float s0 = a0[m], s1 = a1[m], s2 = a2[m], s3 = a3[m];
      s0 += __shfl_xor(s0, 1, 64); s0 += __shfl_xor(s0, 2, 64);
      s1 += __shfl_xor(s1, 1, 64); s1 += __shfl_xor(s1, 2, 64);
      s2 += __shfl_xor(s2, 1, 64); s2 += __shfl_xor(s2, 2, 64);
      s3 += __shfl_xor(s3, 1, 64); s3 += __shfl_xor(s3, 2, 64);
      if (c == 0) {
        float* Ym = Y + (size_t)m * N;
        if (v0) atomicAdd(&Ym[r0], s0);
        if (v1) atomicAdd(&Ym[r1], s1);
        if (v2) atomicAdd(&Ym[r2], s2);
        if (v3) atomicAdd(&Ym[r3], s3);
      }
    }
    __syncthreads();
  }
}

// ---- attention partial (verbatim R3) ---------------------------------------
__global__ __launch_bounds__(256) void attn_partial(
    const float* __restrict__ ht, const float* __restrict__ enc,
    const int* __restrict__ mask, float* __restrict__ part) {
  int b = blockIdx.x;
  int chunk = blockIdx.y;
  int w = threadIdx.x >> 6;
  int l = threadIdx.x & 63;
  int s0 = chunk * ROWS_PER_CHUNK;

  __shared__ int smask[ROWS_PER_CHUNK];
  __shared__ float sml[4][2];
  __shared__ float sacc[4][1024];
  if (threadIdx.x < ROWS_PER_CHUNK)
    smask[threadIdx.x] = mask[(size_t)b * SS + s0 + threadIdx.x];

  const float* encb = enc + (size_t)b * SS * DD;
  const float* htb = ht + (size_t)b * DD;
  float4 h4[4];
#pragma unroll
  for (int j = 0; j < 4; j++) h4[j] = *(const float4*)(htb + 256 * j + 4 * l);
  __syncthreads();

  float4 acc[4];
#pragma unroll
  for (int j = 0; j < 4; j++) acc[j] = make_float4(0.f, 0.f, 0.f, 0.f);
  float mw = -INFINITY, lw = 0.f;

  int rbase = w * 32;
  for (int ii = 0; ii < 8; ii++) {
    int rr = rbase + 4 * ii;
    int mk0 = smask[rr], mk1 = smask[rr + 1], mk2 = smask[rr + 2], mk3 = smask[rr + 3];
    if ((mk0 | mk1 | mk2 | mk3) == 0) continue;
    const float* er = encb + (size_t)(s0 + rr) * DD + 4 * l;
    float4 e0[4], e1[4], e2[4], e3[4];
#pragma unroll
    for (int j = 0; j < 4; j++) {
      e0[j] = *(const float4*)(er + 256 * j);
      e1[j] = *(const float4*)(er + DD + 256 * j);
      e2[j] = *(const float4*)(er + 2 * DD + 256 * j);
      e3[j] = *(const float4*)(er + 3 * DD + 256 * j);
    }
    float p0 = 0.f, p1 = 0.f, p2 = 0.f, p3 = 0.f;
#pragma unroll
    for (int j = 0; j < 4; j++) {
      p0 += e0[j].x * h4[j].x + e0[j].y * h4[j].y + e0[j].z * h4[j].z + e0[j].w * h4[j].w;
      p1 += e1[j].x * h4[j].x + e1[j].y * h4[j].y + e1[j].z * h4[j].z + e1[j].w * h4[j].w;
      p2 += e2[j].x * h4[j].x + e2[j].y * h4[j].y + e2[j].z * h4[j].z + e2[j].w * h4[j].w;
      p3 += e3[j].x * h4[j].x + e3[j].y * h4[j].y + e3[j].z * h4[j].z + e3[j].w * h4[j].w;
    }
#pragma unroll
    for (int off = 32; off; off >>= 1) {
      p0 += __shfl_xor(p0, off, 64);
      p1 += __shfl_xor(p1, off, 64);
      p2 += __shfl_xor(p2, off, 64);
      p3 += __shfl_xor(p3, off, 64);
    }
    if (!mk0) p0 = -INFINITY;
    if (!mk1) p1 = -INFINITY;
    if (!mk2) p2 = -INFINITY;
    if (!mk3) p3 = -INFINITY;
    float mn = fmaxf(fmaxf(mw, fmaxf(p0, p1)), fmaxf(p2, p3));
    if (mn > -INFINITY) {
      float sc = (mw > -INFINITY) ? __expf(mw - mn) : 0.f;
      float a0 = __expf(p0 - mn);
      float a1 = __expf(p1 - mn);
      float a2 = __expf(p2 - mn);
      float a3 = __expf(p3 - mn);
      lw = lw * sc + (a0 + a1) + (a2 + a3);
#pragma unroll
      for (int j = 0; j < 4; j++) {
        acc[j].x = acc[j].x * sc + a0 * e0[j].x + a1 * e1[j].x + a2 * e2[j].x + a3 * e3[j].x;
        acc[j].y = acc[j].y * sc + a0 * e0[j].y + a1 * e1[j].y + a2 * e2[j].y + a3 * e3[j].y;
        acc[j].z = acc[j].z * sc + a0 * e0[j].z + a1 * e1[j].z + a2 * e2[j].z + a3 * e3[j].z;
        acc[j].w = acc[j].w * sc + a0 * e0[j].w + a1 * e1[j].w + a2 * e2[j].w + a3 * e3[j].w;
      }
      mw = mn;
    }
  }

  if (l == 0) { sml[w][0] = mw; sml[w][1] = lw; }
#pragma unroll
  for (int j = 0; j < 4; j++) *(float4*)&sacc[w][256 * j + 4 * l] = acc[j];
  __syncthreads();

  float M = fmaxf(fmaxf(sml[0][0], sml[1][0]), fmaxf(sml[2][0], sml[3][0]));
  float L = 0.f;
  float scw[4];
#pragma unroll
  for (int ww = 0; ww < 4; ww++) {
    float mm = sml[ww][0];
    float s_ = (mm == -INFINITY) ? 0.f : __expf(mm - M);
    scw[ww] = s_;
    L += sml[ww][1] * s_;
  }
  float* P = part + (size_t)(b * NCHUNK + chunk) * PART_STRIDE;
  int tid = threadIdx.x;
  if (tid == 0) { P[0] = M; P[1] = L; }
  float4 u = make_float4(0.f, 0.f, 0.f, 0.f);
#pragma unroll
  for (int ww = 0; ww < 4; ww++) {
    float4 a = *(const float4*)&sacc[ww][4 * tid];
    u.x += scw[ww] * a.x; u.y += scw[ww] * a.y;
    u.z += scw[ww] * a.z; u.w += scw[ww] * a.w;
  }
  *(float4*)&P[8 + 4 * tid] = u;
}

// ---- combine partials; xcat = [h_t | summary]  (verbatim R3) ---------------
__global__ __launch_bounds__(256) void attn_reduce(
    const float* __restrict__ part, const float* __restrict__ ht,
    float* __restrict__ xcat) {
  int b = blockIdx.x;
  int tid = threadIdx.x;
  const float* Pb = part + (size_t)b * NCHUNK * PART_STRIDE;
  float M = -INFINITY;
#pragma unroll
  for (int c = 0; c < NCHUNK; c++) M = fmaxf(M, Pb[c * PART_STRIDE]);
  float L = 0.f;
  float sc[NCHUNK];
#pragma unroll
  for (int c = 0; c < NCHUNK; c++) {
    float mc = Pb[c * PART_STRIDE];
    float s_ = (mc == -INFINITY) ? 0.f : __expf(mc - M);
    sc[c] = s_;
    L += Pb[c * PART_STRIDE + 1] * s_;
  }
  float inv = (L > 0.f) ? 1.f / L : 0.f;
  float4 u = make_float4(0.f, 0.f, 0.f, 0.f);
#pragma unroll
  for (int c = 0; c < NCHUNK; c++) {
    float4 a = *(const float4*)&Pb[c * PART_STRIDE + 8 + 4 * tid];
    u.x += sc[c] * a.x; u.y += sc[c] * a.y;
    u.z += sc[c] * a.z; u.w += sc[c] * a.w;
  }
  u.x *= inv; u.y *= inv; u.z *= inv; u.w *= inv;
  *(float4*)&xcat[(size_t)b * 2048 + 1024 + 4 * tid] = u;
  *(float4*)&xcat[(size_t)b * 2048 + 4 * tid] = *(const float4*)&ht[(size_t)b * DD + 4 * tid];
}

extern "C" void kernel_launch(void* const* d_in, const int* in_sizes, int n_in,
                              void* d_out, int out_size, void* d_ws, size_t ws_size,
                              hipStream_t stream) {
  const int*   tokens  = (const int*)d_in[0];
  const float* enc     = (const float*)d_in[1];
  const int*   encmask = (const int*)d_in[2];
  const float* emb     = (const float*)d_in[3];
  const float* Wih0    = (const float*)d_in[4];
  const float* bih0    = (const float*)d_in[6];
  const float* bhh0    = (const float*)d_in[7];
  const float* Wih1    = (const float*)d_in[8];
  const float* bih1    = (const float*)d_in[10];
  const float* bhh1    = (const float*)d_in[11];
  const float* preoutW = (const float*)d_in[12];
  const float* preoutb = (const float*)d_in[13];
  const float* outW    = (const float*)d_in[14];
  const float* outb    = (const float*)d_in[15];
  float* out = (float*)d_out;
  float* ws  = (float*)d_ws;

  float* embs = ws;                            // 32*1024
  float* gi0  = embs + 32 * 1024;              // 32*3072
  float* h    = gi0 + 32 * 3072;               // 32*1024
  float* gi1  = h + 32 * 1024;                 // 32*3072
  float* ht   = gi1 + 32 * 3072;               // 32*1024
  float* part = ht + 32 * 1024;                // 32*32*1032
  float* xcat = part + 32 * 32 * PART_STRIDE;  // 32*2048
  float* opre = xcat + 32 * 2048;              // 32*1024
  float* scr1 = opre + 32 * 1024;              // probe scratch 32*VVOUT

  pre_layer0<<<384, 256, 0, stream>>>(tokens, emb, embs, bih0, gi0);
  mm_lds<128><<<dim3(48, 8), 256, 0, stream>>>(gi0, embs, Wih0, 3072, 2048, 1024);
  act0_fill<<<384, 256, 0, stream>>>(gi0, bhh0, h, bih1, gi1);
  mm_lds<128><<<dim3(48, 8), 256, 0, stream>>>(gi1, h, Wih1, 3072, 1024, 1024);
  act1_fill<<<4001, 256, 0, stream>>>(gi1, bhh1, ht, preoutb, opre, outb, out);

  attn_partial<<<dim3(BB, NCHUNK), 256, 0, stream>>>(ht, enc, encmask, part);
  attn_reduce<<<BB, 256, 0, stream>>>(part, ht, xcat);

  mm_lds<128><<<dim3(16, 16), 256, 0, stream>>>(opre, xcat, preoutW, 1024, 2048, 2048);

  // logits: 128 rows/block, 2-row blocking per lane-group, k-split 4
  logits_mm2<256><<<dim3(251, 4), 256, 0, stream>>>(out, opre, outW, VVOUT, 1024, 1024);

  // probe: R18's 4-row variant x12 (scratch) -> counters in top-5
  pmm4<128, 12><<<dim3(126, 8), 256, 0, stream>>>(scr1, opre, outW, VVOUT, 1024, 1024);
}

// Round 20
// 231.663 us; speedup vs baseline: 4.0926x; 4.0926x over previous
//
#include <hip/hip_runtime.h>
#include <math.h>

#define BB 32
#define DD 1024
#define SS 4096
#define VVOUT 32003
#define NCHUNK 32
#define ROWS_PER_CHUNK 128
#define PART_STRIDE 1032

// ---- k1: gather embeddings AND prefill gi0 with bih0 -----------------------
__global__ void pre_layer0(const int* __restrict__ tokens, const float* __restrict__ emb,
                           float* __restrict__ embs, const float* __restrict__ bih0,
                           float* __restrict__ gi0) {
  int i = blockIdx.x * 256 + threadIdx.x;
  if (i < 32 * 1024) embs[i] = emb[(size_t)tokens[i >> 10] * DD + (i & 1023)];
  if (i < 32 * 3072) gi0[i] = bih0[i - (i / 3072) * 3072];
}

// ---- k3: gru_act layer0 AND prefill gi1 with bih1 --------------------------
__global__ void act0_fill(const float* __restrict__ gi, const float* __restrict__ bhh,
                          float* __restrict__ h, const float* __restrict__ bih1,
                          float* __restrict__ gi1) {
  int i = blockIdx.x * 256 + threadIdx.x;
  if (i < 32 * 1024) {
    int m = i >> 10, d = i & 1023;
    const float* g = gi + (size_t)m * 3072;
    float ir = g[d], iz = g[d + 1024], inn = g[d + 2048];
    float r = 1.f / (1.f + expf(-(ir + bhh[d])));
    float z = 1.f / (1.f + expf(-(iz + bhh[1024 + d])));
    float nv = tanhf(inn + r * bhh[2048 + d]);
    h[i] = (1.f - z) * nv;
  }
  if (i < 32 * 3072) gi1[i] = bih1[i - (i / 3072) * 3072];
}

// ---- k5: gru_act layer1 AND prefill opre (preoutb) AND out (outb) ----------
__global__ void act1_fill(const float* __restrict__ gi, const float* __restrict__ bhh,
                          float* __restrict__ ht, const float* __restrict__ preoutb,
                          float* __restrict__ opre, const float* __restrict__ outb,
                          float* __restrict__ out) {
  int i = blockIdx.x * 256 + threadIdx.x;
  if (i < 32 * 1024) {
    int m = i >> 10, d = i & 1023;
    const float* g = gi + (size_t)m * 3072;
    float ir = g[d], iz = g[d + 1024], inn = g[d + 2048];
    float r = 1.f / (1.f + expf(-(ir + bhh[d])));
    float z = 1.f / (1.f + expf(-(iz + bhh[1024 + d])));
    float nv = tanhf(inn + r * bhh[2048 + d]);
    ht[i] = (1.f - z) * nv;
    opre[i] = preoutb[d];
  }
  if (i < 32 * VVOUT) out[i] = outb[i - (i / VVOUT) * VVOUT];
}

// ---- GEMM with LDS-staged X (verbatim R16) ---------------------------------
template <int KCHUNK>
__global__ __launch_bounds__(256) void mm_lds(
    float* __restrict__ Y, const float* __restrict__ X, const float* __restrict__ W,
    int N, int ldw, int xld) {
  __shared__ float xs[32][KCHUNK];
  int k0 = blockIdx.y * KCHUNK;
  for (int idx = threadIdx.x; idx < 32 * (KCHUNK / 4); idx += 256) {
    int m = idx / (KCHUNK / 4);
    int i = idx - m * (KCHUNK / 4);
    *(float4*)&xs[m][4 * i] = *(const float4*)(X + (size_t)m * xld + k0 + 4 * i);
  }
  __syncthreads();

  int lane = threadIdx.x & 63;
  int w = threadIdx.x >> 6;
  int c = lane & 3;
  int r = blockIdx.x * 64 + w * 16 + (lane >> 2);
  bool valid = r < N;
  int rr = valid ? r : N - 1;
  const float* wrow = W + (size_t)rr * ldw + k0 + 4 * c;

  float acc[BB];
#pragma unroll
  for (int m = 0; m < BB; m++) acc[m] = 0.f;
#pragma unroll 4
  for (int kk = 0; kk < KCHUNK; kk += 16) {
    float4 w4 = *(const float4*)(wrow + kk);
#pragma unroll
    for (int m = 0; m < BB; m++) {
      float4 x4 = *(const float4*)&xs[m][kk + 4 * c];
      acc[m] = fmaf(w4.x, x4.x, fmaf(w4.y, x4.y, fmaf(w4.z, x4.z, fmaf(w4.w, x4.w, acc[m]))));
    }
  }
#pragma unroll
  for (int m = 0; m < BB; m++) {
    float v = acc[m];
    v += __shfl_xor(v, 1, 64);
    v += __shfl_xor(v, 2, 64);
    if (c == 0 && valid) atomicAdd(&Y[(size_t)m * N + r], v);
  }
}

// ---- logits GEMM, 2-row blocking: one xs read feeds 8 FMAs -----------------
template <int KCHUNK>
__global__ __launch_bounds__(256) void logits_mm2(
    float* __restrict__ Y, const float* __restrict__ X, const float* __restrict__ W,
    int N, int ldw, int xld) {
  __shared__ float xs[32][KCHUNK];
  int k0 = blockIdx.y * KCHUNK;
  for (int idx = threadIdx.x; idx < 32 * (KCHUNK / 4); idx += 256) {
    int m = idx / (KCHUNK / 4);
    int i = idx - m * (KCHUNK / 4);
    *(float4*)&xs[m][4 * i] = *(const float4*)(X + (size_t)m * xld + k0 + 4 * i);
  }
  __syncthreads();

  int lane = threadIdx.x & 63;
  int w = threadIdx.x >> 6;
  int c = lane & 3;
  int g = lane >> 2;                       // 0..15
  int rb = blockIdx.x * 128 + w * 32 + g;  // rows rb, rb+16
  int r0 = rb, r1 = rb + 16;
  bool v0 = r0 < N, v1 = r1 < N;
  const float* w0p = W + (size_t)(v0 ? r0 : N - 1) * ldw + k0 + 4 * c;
  const float* w1p = W + (size_t)(v1 ? r1 : N - 1) * ldw + k0 + 4 * c;

  float a0[BB], a1[BB];
#pragma unroll
  for (int m = 0; m < BB; m++) { a0[m] = 0.f; a1[m] = 0.f; }

#pragma unroll 4
  for (int kk = 0; kk < KCHUNK; kk += 16) {
    float4 w40 = *(const float4*)(w0p + kk);
    float4 w41 = *(const float4*)(w1p + kk);
#pragma unroll
    for (int m = 0; m < BB; m++) {
      float4 x4 = *(const float4*)&xs[m][kk + 4 * c];
      a0[m] = fmaf(w40.x, x4.x, fmaf(w40.y, x4.y, fmaf(w40.z, x4.z, fmaf(w40.w, x4.w, a0[m]))));
      a1[m] = fmaf(w41.x, x4.x, fmaf(w41.y, x4.y, fmaf(w41.z, x4.z, fmaf(w41.w, x4.w, a1[m]))));
    }
  }
#pragma unroll
  for (int m = 0; m < BB; m++) {
    float s0 = a0[m], s1 = a1[m];
    s0 += __shfl_xor(s0, 1, 64); s0 += __shfl_xor(s0, 2, 64);
    s1 += __shfl_xor(s1, 1, 64); s1 += __shfl_xor(s1, 2, 64);
    if (c == 0) {
      float* Ym = Y + (size_t)m * N;
      if (v0) atomicAdd(&Ym[r0], s0);
      if (v1) atomicAdd(&Ym[r1], s1);
    }
  }
}

// ---- attention partial (verbatim R3) ---------------------------------------
__global__ __launch_bounds__(256) void attn_partial(
    const float* __restrict__ ht, const float* __restrict__ enc,
    const int* __restrict__ mask, float* __restrict__ part) {
  int b = blockIdx.x;
  int chunk = blockIdx.y;
  int w = threadIdx.x >> 6;
  int l = threadIdx.x & 63;
  int s0 = chunk * ROWS_PER_CHUNK;

  __shared__ int smask[ROWS_PER_CHUNK];
  __shared__ float sml[4][2];
  __shared__ float sacc[4][1024];
  if (threadIdx.x < ROWS_PER_CHUNK)
    smask[threadIdx.x] = mask[(size_t)b * SS + s0 + threadIdx.x];

  const float* encb = enc + (size_t)b * SS * DD;
  const float* htb = ht + (size_t)b * DD;
  float4 h4[4];
#pragma unroll
  for (int j = 0; j < 4; j++) h4[j] = *(const float4*)(htb + 256 * j + 4 * l);
  __syncthreads();

  float4 acc[4];
#pragma unroll
  for (int j = 0; j < 4; j++) acc[j] = make_float4(0.f, 0.f, 0.f, 0.f);
  float mw = -INFINITY, lw = 0.f;

  int rbase = w * 32;
  for (int ii = 0; ii < 8; ii++) {
    int rr = rbase + 4 * ii;
    int mk0 = smask[rr], mk1 = smask[rr + 1], mk2 = smask[rr + 2], mk3 = smask[rr + 3];
    if ((mk0 | mk1 | mk2 | mk3) == 0) continue;
    const float* er = encb + (size_t)(s0 + rr) * DD + 4 * l;
    float4 e0[4], e1[4], e2[4], e3[4];
#pragma unroll
    for (int j = 0; j < 4; j++) {
      e0[j] = *(const float4*)(er + 256 * j);
      e1[j] = *(const float4*)(er + DD + 256 * j);
      e2[j] = *(const float4*)(er + 2 * DD + 256 * j);
      e3[j] = *(const float4*)(er + 3 * DD + 256 * j);
    }
    float p0 = 0.f, p1 = 0.f, p2 = 0.f, p3 = 0.f;
#pragma unroll
    for (int j = 0; j < 4; j++) {
      p0 += e0[j].x * h4[j].x + e0[j].y * h4[j].y + e0[j].z * h4[j].z + e0[j].w * h4[j].w;
      p1 += e1[j].x * h4[j].x + e1[j].y * h4[j].y + e1[j].z * h4[j].z + e1[j].w * h4[j].w;
      p2 += e2[j].x * h4[j].x + e2[j].y * h4[j].y + e2[j].z * h4[j].z + e2[j].w * h4[j].w;
      p3 += e3[j].x * h4[j].x + e3[j].y * h4[j].y + e3[j].z * h4[j].z + e3[j].w * h4[j].w;
    }
#pragma unroll
    for (int off = 32; off; off >>= 1) {
      p0 += __shfl_xor(p0, off, 64);
      p1 += __shfl_xor(p1, off, 64);
      p2 += __shfl_xor(p2, off, 64);
      p3 += __shfl_xor(p3, off, 64);
    }
    if (!mk0) p0 = -INFINITY;
    if (!mk1) p1 = -INFINITY;
    if (!mk2) p2 = -INFINITY;
    if (!mk3) p3 = -INFINITY;
    float mn = fmaxf(fmaxf(mw, fmaxf(p0, p1)), fmaxf(p2, p3));
    if (mn > -INFINITY) {
      float sc = (mw > -INFINITY) ? __expf(mw - mn) : 0.f;
      float a0 = __expf(p0 - mn);
      float a1 = __expf(p1 - mn);
      float a2 = __expf(p2 - mn);
      float a3 = __expf(p3 - mn);
      lw = lw * sc + (a0 + a1) + (a2 + a3);
#pragma unroll
      for (int j = 0; j < 4; j++) {
        acc[j].x = acc[j].x * sc + a0 * e0[j].x + a1 * e1[j].x + a2 * e2[j].x + a3 * e3[j].x;
        acc[j].y = acc[j].y * sc + a0 * e0[j].y + a1 * e1[j].y + a2 * e2[j].y + a3 * e3[j].y;
        acc[j].z = acc[j].z * sc + a0 * e0[j].z + a1 * e1[j].z + a2 * e2[j].z + a3 * e3[j].z;
        acc[j].w = acc[j].w * sc + a0 * e0[j].w + a1 * e1[j].w + a2 * e2[j].w + a3 * e3[j].w;
      }
      mw = mn;
    }
  }

  if (l == 0) { sml[w][0] = mw; sml[w][1] = lw; }
#pragma unroll
  for (int j = 0; j < 4; j++) *(float4*)&sacc[w][256 * j + 4 * l] = acc[j];
  __syncthreads();

  float M = fmaxf(fmaxf(sml[0][0], sml[1][0]), fmaxf(sml[2][0], sml[3][0]));
  float L = 0.f;
  float scw[4];
#pragma unroll
  for (int ww = 0; ww < 4; ww++) {
    float mm = sml[ww][0];
    float s_ = (mm == -INFINITY) ? 0.f : __expf(mm - M);
    scw[ww] = s_;
    L += sml[ww][1] * s_;
  }
  float* P = part + (size_t)(b * NCHUNK + chunk) * PART_STRIDE;
  int tid = threadIdx.x;
  if (tid == 0) { P[0] = M; P[1] = L; }
  float4 u = make_float4(0.f, 0.f, 0.f, 0.f);
#pragma unroll
  for (int ww = 0; ww < 4; ww++) {
    float4 a = *(const float4*)&sacc[ww][4 * tid];
    u.x += scw[ww] * a.x; u.y += scw[ww] * a.y;
    u.z += scw[ww] * a.z; u.w += scw[ww] * a.w;
  }
  *(float4*)&P[8 + 4 * tid] = u;
}

// ---- combine partials; xcat = [h_t | summary]  (verbatim R3) ---------------
__global__ __launch_bounds__(256) void attn_reduce(
    const float* __restrict__ part, const float* __restrict__ ht,
    float* __restrict__ xcat) {
  int b = blockIdx.x;
  int tid = threadIdx.x;
  const float* Pb = part + (size_t)b * NCHUNK * PART_STRIDE;
  float M = -INFINITY;
#pragma unroll
  for (int c = 0; c < NCHUNK; c++) M = fmaxf(M, Pb[c * PART_STRIDE]);
  float L = 0.f;
  float sc[NCHUNK];
#pragma unroll
  for (int c = 0; c < NCHUNK; c++) {
    float mc = Pb[c * PART_STRIDE];
    float s_ = (mc == -INFINITY) ? 0.f : __expf(mc - M);
    sc[c] = s_;
    L += Pb[c * PART_STRIDE + 1] * s_;
  }
  float inv = (L > 0.f) ? 1.f / L : 0.f;
  float4 u = make_float4(0.f, 0.f, 0.f, 0.f);
#pragma unroll
  for (int c = 0; c < NCHUNK; c++) {
    float4 a = *(const float4*)&Pb[c * PART_STRIDE + 8 + 4 * tid];
    u.x += sc[c] * a.x; u.y += sc[c] * a.y;
    u.z += sc[c] * a.z; u.w += sc[c] * a.w;
  }
  u.x *= inv; u.y *= inv; u.z *= inv; u.w *= inv;
  *(float4*)&xcat[(size_t)b * 2048 + 1024 + 4 * tid] = u;
  *(float4*)&xcat[(size_t)b * 2048 + 4 * tid] = *(const float4*)&ht[(size_t)b * DD + 4 * tid];
}

extern "C" void kernel_launch(void* const* d_in, const int* in_sizes, int n_in,
                              void* d_out, int out_size, void* d_ws, size_t ws_size,
                              hipStream_t stream) {
  const int*   tokens  = (const int*)d_in[0];
  const float* enc     = (const float*)d_in[1];
  const int*   encmask = (const int*)d_in[2];
  const float* emb     = (const float*)d_in[3];
  const float* Wih0    = (const float*)d_in[4];
  const float* bih0    = (const float*)d_in[6];
  const float* bhh0    = (const float*)d_in[7];
  const float* Wih1    = (const float*)d_in[8];
  const float* bih1    = (const float*)d_in[10];
  const float* bhh1    = (const float*)d_in[11];
  const float* preoutW = (const float*)d_in[12];
  const float* preoutb = (const float*)d_in[13];
  const float* outW    = (const float*)d_in[14];
  const float* outb    = (const float*)d_in[15];
  float* out = (float*)d_out;
  float* ws  = (float*)d_ws;

  float* embs = ws;                            // 32*1024
  float* gi0  = embs + 32 * 1024;              // 32*3072
  float* h    = gi0 + 32 * 3072;               // 32*1024
  float* gi1  = h + 32 * 1024;                 // 32*3072
  float* ht   = gi1 + 32 * 3072;               // 32*1024
  float* part = ht + 32 * 1024;                // 32*32*1032
  float* xcat = part + 32 * 32 * PART_STRIDE;  // 32*2048
  float* opre = xcat + 32 * 2048;              // 32*1024

  pre_layer0<<<384, 256, 0, stream>>>(tokens, emb, embs, bih0, gi0);
  mm_lds<128><<<dim3(48, 8), 256, 0, stream>>>(gi0, embs, Wih0, 3072, 2048, 1024);
  act0_fill<<<384, 256, 0, stream>>>(gi0, bhh0, h, bih1, gi1);
  mm_lds<128><<<dim3(48, 8), 256, 0, stream>>>(gi1, h, Wih1, 3072, 1024, 1024);
  act1_fill<<<4001, 256, 0, stream>>>(gi1, bhh1, ht, preoutb, opre, outb, out);

  attn_partial<<<dim3(BB, NCHUNK), 256, 0, stream>>>(ht, enc, encmask, part);
  attn_reduce<<<BB, 256, 0, stream>>>(part, ht, xcat);

  mm_lds<128><<<dim3(16, 16), 256, 0, stream>>>(opre, xcat, preoutW, 1024, 2048, 2048);

  // logits: 128 rows/block, 2-row blocking per lane-group, k-split 4
  logits_mm2<256><<<dim3(251, 4), 256, 0, stream>>>(out, opre, outW, VVOUT, 1024, 1024);
}